// Round 2
// baseline (258.958 us; speedup 1.0000x reference)
//
#include <hip/hip_runtime.h>

#define ALPHA 10.0f
#define BN_EPS 1e-5f
#define NVOX 32768   // 32*32*32
#define MDB 4096

// Bit-identical distance used by BOTH kNN passes (explicit fmaf chain, no
// contraction ambiguity). db rows and q are unit vectors, so
// d2 = ||q||^2 + ||r||^2 - 2 q.r == 2 - 2 q.r up to ~1e-7 (irrelevant for
// selection and for exp(-10 d2)).
__device__ __forceinline__ float dist2(const float4 qa, const float4 qb,
                                       const float4 r0, const float4 r1) {
  float pA = qa.x * r0.x;
  pA = fmaf(qa.y, r0.y, pA);
  pA = fmaf(qa.z, r0.z, pA);
  pA = fmaf(qa.w, r0.w, pA);
  float pB = qb.x * r1.x;
  pB = fmaf(qb.y, r1.y, pB);
  pB = fmaf(qb.z, r1.z, pB);
  pB = fmaf(qb.w, r1.w, pB);
  return fmaxf(fmaf(-2.f, pA + pB, 2.f), 0.f);
}

// Insert nd into sorted-ascending d[0..9] keeping the 10 smallest.
// Identity: d'[k] = min(max(d[k-1], nd), d[k]); update k descending so the
// old d[k-1] is read. 19 v_min/v_max, no vcc, dependency depth 2.
#define INSERT10(d, nd)                                   \
  do {                                                    \
    _Pragma("unroll")                                     \
    for (int _k = 9; _k >= 1; --_k)                       \
      d[_k] = fminf(fmaxf(d[_k - 1], (nd)), d[_k]);       \
    d[0] = fminf(d[0], (nd));                             \
  } while (0)

// ---------------- conv1: 2->16, k3, pad1, +BN+ReLU ----------------
__global__ __launch_bounds__(256) void k_conv1(
    const float* __restrict__ bg, const float* __restrict__ ed,
    const float* __restrict__ w1, const float* __restrict__ b1,
    const float* __restrict__ g1, const float* __restrict__ be1,
    const float* __restrict__ m1, const float* __restrict__ v1,
    float* __restrict__ A) {
  __shared__ float wT[54 * 16];  // [c*27+kk][o]
  __shared__ float sc[16], sh[16];
  int t = threadIdx.x;
  for (int i = t; i < 864; i += 256) {
    int o = i & 15, r = i >> 4;       // r = c*27+kk
    wT[i] = w1[o * 54 + r];
  }
  if (t < 16) {
    float s = g1[t] * rsqrtf(v1[t] + BN_EPS);
    sc[t] = s;
    sh[t] = (b1[t] - m1[t]) * s + be1[t];
  }
  __syncthreads();
  int v = blockIdx.x * 256 + t;
  int x = v & 31, y = (v >> 5) & 31, z = v >> 10;
  float acc[16];
#pragma unroll
  for (int o = 0; o < 16; ++o) acc[o] = 0.f;
#pragma unroll 1
  for (int k = 0; k < 27; ++k) {
    int dz = k / 9 - 1, dy = (k / 3) % 3 - 1, dx = k % 3 - 1;
    int zz = z + dz, yy = y + dy, xx = x + dx;
    bool inb = (unsigned)zz < 32u && (unsigned)yy < 32u && (unsigned)xx < 32u;
    int vv = zz * 1024 + yy * 32 + xx;
#pragma unroll
    for (int c = 0; c < 2; ++c) {
      const float* in = c ? ed : bg;
      float val = inb ? in[vv] : 0.f;
      const float4* wp = (const float4*)&wT[(c * 27 + k) * 16];
      float4 wa = wp[0], wb = wp[1], wc = wp[2], wd = wp[3];
      acc[0] = fmaf(val, wa.x, acc[0]);  acc[1] = fmaf(val, wa.y, acc[1]);
      acc[2] = fmaf(val, wa.z, acc[2]);  acc[3] = fmaf(val, wa.w, acc[3]);
      acc[4] = fmaf(val, wb.x, acc[4]);  acc[5] = fmaf(val, wb.y, acc[5]);
      acc[6] = fmaf(val, wb.z, acc[6]);  acc[7] = fmaf(val, wb.w, acc[7]);
      acc[8] = fmaf(val, wc.x, acc[8]);  acc[9] = fmaf(val, wc.y, acc[9]);
      acc[10] = fmaf(val, wc.z, acc[10]); acc[11] = fmaf(val, wc.w, acc[11]);
      acc[12] = fmaf(val, wd.x, acc[12]); acc[13] = fmaf(val, wd.y, acc[13]);
      acc[14] = fmaf(val, wd.z, acc[14]); acc[15] = fmaf(val, wd.w, acc[15]);
    }
  }
#pragma unroll
  for (int o = 0; o < 16; ++o) {
    float y2 = fmaf(acc[o], sc[o], sh[o]);
    A[o * NVOX + v] = y2 > 0.f ? y2 : 0.f;
  }
}

// ---------------- conv2: 16->32, k3, pad1, +BN+ReLU ----------------
__global__ __launch_bounds__(256) void k_conv2(
    const float* __restrict__ A, const float* __restrict__ w2,
    const float* __restrict__ b2, const float* __restrict__ g2,
    const float* __restrict__ be2, const float* __restrict__ m2,
    const float* __restrict__ v2, float* __restrict__ B) {
  __shared__ float wT[432 * 16];  // [ci*27+kk][o16]
  __shared__ float sc[16], sh[16];
  int t = threadIdx.x;
  int h = blockIdx.x >> 7;   // 0/1 -> which 16 output channels
  int vb = blockIdx.x & 127;
  for (int i = t; i < 6912; i += 256) {
    int o = i & 15, r = i >> 4;  // r = ci*27+kk
    wT[i] = w2[(h * 16 + o) * 432 + r];
  }
  if (t < 16) {
    int o = h * 16 + t;
    float s = g2[o] * rsqrtf(v2[o] + BN_EPS);
    sc[t] = s;
    sh[t] = (b2[o] - m2[o]) * s + be2[o];
  }
  __syncthreads();
  int v = vb * 256 + t;
  int x = v & 31, y = (v >> 5) & 31, z = v >> 10;
  float acc[16];
#pragma unroll
  for (int o = 0; o < 16; ++o) acc[o] = 0.f;
#pragma unroll 1
  for (int k = 0; k < 27; ++k) {
    int dz = k / 9 - 1, dy = (k / 3) % 3 - 1, dx = k % 3 - 1;
    int zz = z + dz, yy = y + dy, xx = x + dx;
    bool inb = (unsigned)zz < 32u && (unsigned)yy < 32u && (unsigned)xx < 32u;
    int vv = zz * 1024 + yy * 32 + xx;
#pragma unroll
    for (int ci = 0; ci < 16; ++ci) {
      float val = inb ? A[ci * NVOX + vv] : 0.f;
      const float4* wp = (const float4*)&wT[(ci * 27 + k) * 16];
      float4 wa = wp[0], wb = wp[1], wc = wp[2], wd = wp[3];
      acc[0] = fmaf(val, wa.x, acc[0]);  acc[1] = fmaf(val, wa.y, acc[1]);
      acc[2] = fmaf(val, wa.z, acc[2]);  acc[3] = fmaf(val, wa.w, acc[3]);
      acc[4] = fmaf(val, wb.x, acc[4]);  acc[5] = fmaf(val, wb.y, acc[5]);
      acc[6] = fmaf(val, wb.z, acc[6]);  acc[7] = fmaf(val, wb.w, acc[7]);
      acc[8] = fmaf(val, wc.x, acc[8]);  acc[9] = fmaf(val, wc.y, acc[9]);
      acc[10] = fmaf(val, wc.z, acc[10]); acc[11] = fmaf(val, wc.w, acc[11]);
      acc[12] = fmaf(val, wd.x, acc[12]); acc[13] = fmaf(val, wd.y, acc[13]);
      acc[14] = fmaf(val, wd.z, acc[14]); acc[15] = fmaf(val, wd.w, acc[15]);
    }
  }
#pragma unroll
  for (int o = 0; o < 16; ++o) {
    float y2 = fmaf(acc[o], sc[o], sh[o]);
    B[(h * 16 + o) * NVOX + v] = y2 > 0.f ? y2 : 0.f;
  }
}

// ---------------- conv3 (1x1x1) 32->8 + L2 normalize ----------------
__global__ __launch_bounds__(256) void k_conv3(
    const float* __restrict__ B, const float* __restrict__ w3,
    const float* __restrict__ b3, float* __restrict__ Q) {
  __shared__ float wT[32 * 8];  // [ci][o]
  __shared__ float bL[8];
  int t = threadIdx.x;
  if (t < 256) {
    int o = t & 7, ci = t >> 3;
    wT[t] = w3[o * 32 + ci];
  }
  if (t < 8) bL[t] = b3[t];
  __syncthreads();
  int v = blockIdx.x * 256 + t;
  float lat[8];
#pragma unroll
  for (int o = 0; o < 8; ++o) lat[o] = bL[o];
#pragma unroll 4
  for (int ci = 0; ci < 32; ++ci) {
    float val = B[ci * NVOX + v];
    const float4* wp = (const float4*)&wT[ci * 8];
    float4 wa = wp[0], wb = wp[1];
    lat[0] = fmaf(val, wa.x, lat[0]); lat[1] = fmaf(val, wa.y, lat[1]);
    lat[2] = fmaf(val, wa.z, lat[2]); lat[3] = fmaf(val, wa.w, lat[3]);
    lat[4] = fmaf(val, wb.x, lat[4]); lat[5] = fmaf(val, wb.y, lat[5]);
    lat[6] = fmaf(val, wb.z, lat[6]); lat[7] = fmaf(val, wb.w, lat[7]);
  }
  float n2 = 0.f;
#pragma unroll
  for (int o = 0; o < 8; ++o) n2 = fmaf(lat[o], lat[o], n2);
  float inv = 1.f / fmaxf(sqrtf(n2), 1e-12f);
  float4 qa, qb;
  qa.x = lat[0] * inv; qa.y = lat[1] * inv; qa.z = lat[2] * inv; qa.w = lat[3] * inv;
  qb.x = lat[4] * inv; qb.y = lat[5] * inv; qb.z = lat[6] * inv; qb.w = lat[7] * inv;
  ((float4*)(Q + (size_t)v * 8))[0] = qa;
  ((float4*)(Q + (size_t)v * 8))[1] = qb;
}

// ---------------- kNN pass 1: per-(query,chunk) top-10 DISTANCES only ------
__global__ __launch_bounds__(256) void k_knn1(
    const float* __restrict__ Q, const float* __restrict__ db,
    float* __restrict__ pk, int nchunk) {
  int t = threadIdx.x;
  int c = blockIdx.x >> 7;
  int v = (blockIdx.x & 127) * 256 + t;
  int L = MDB / nchunk;
  int j0 = c * L, j1 = j0 + L;
  float4 qa = ((const float4*)(Q + (size_t)v * 8))[0];
  float4 qb = ((const float4*)(Q + (size_t)v * 8))[1];
  float d[10];
#pragma unroll
  for (int k = 0; k < 10; ++k) d[k] = 3.4e38f;
#pragma unroll 4
  for (int j = j0; j < j1; ++j) {
    float4 r0 = ((const float4*)(db + (size_t)j * 8))[0];
    float4 r1 = ((const float4*)(db + (size_t)j * 8))[1];
    float nd = dist2(qa, qb, r0, r1);
    INSERT10(d, nd);  // unconditional: wave-level branch is ~always taken anyway
  }
  // layout [c][k][v] -> coalesced stores and merge reads
#pragma unroll
  for (int k = 0; k < 10; ++k) pk[((size_t)c * 10 + k) * NVOX + v] = d[k];
}

// ---------------- merge partial top-10s -> exact 10th-smallest threshold ----
__global__ __launch_bounds__(256) void k_merge1(
    const float* __restrict__ pk, float* __restrict__ T, int nchunk) {
  int v = blockIdx.x * 256 + threadIdx.x;
  float d[10];
#pragma unroll
  for (int k = 0; k < 10; ++k) d[k] = 3.4e38f;
#pragma unroll 1
  for (int c = 0; c < nchunk; ++c) {
#pragma unroll
    for (int k2 = 0; k2 < 10; ++k2) {
      float nd = pk[((size_t)c * 10 + k2) * NVOX + v];
      INSERT10(d, nd);
    }
  }
  T[v] = d[9];  // exact 10th smallest distance for this query
}

// ---------------- kNN pass 2: accumulate exp-weighted labels for d2 <= T ----
__global__ __launch_bounds__(256) void k_knn2(
    const float* __restrict__ Q, const float* __restrict__ db,
    const float* __restrict__ T, const float* __restrict__ labels,
    float2* __restrict__ nd_out, int nchunk) {
  int t = threadIdx.x;
  int c = blockIdx.x >> 7;
  int v = (blockIdx.x & 127) * 256 + t;
  int L = MDB / nchunk;
  int j0 = c * L, j1 = j0 + L;
  float4 qa = ((const float4*)(Q + (size_t)v * 8))[0];
  float4 qb = ((const float4*)(Q + (size_t)v * 8))[1];
  float Tv = T[v];
  float num = 0.f, den = 0.f;
#pragma unroll 4
  for (int j = j0; j < j1; ++j) {
    float4 r0 = ((const float4*)(db + (size_t)j * 8))[0];
    float4 r1 = ((const float4*)(db + (size_t)j * 8))[1];
    float lj = labels[j];  // uniform scalar load, outside the branch
    float d2v = dist2(qa, qb, r0, r1);
    if (d2v <= Tv) {  // exactly the top-10 set (ties at T measure-zero)
      float w = __expf(-ALPHA * d2v);
      num = fmaf(w, lj, num);
      den += w;
    }
  }
  nd_out[(size_t)c * NVOX + v] = make_float2(num, den);
}

// ---------------- final reduction over pass-2 chunks ----------------
__global__ __launch_bounds__(256) void k_out(
    const float2* __restrict__ nd_in, float* __restrict__ out, int nchunk) {
  int v = blockIdx.x * 256 + threadIdx.x;
  float num = 0.f, den = 0.f;
#pragma unroll 1
  for (int c = 0; c < nchunk; ++c) {
    float2 p = nd_in[(size_t)c * NVOX + v];
    num += p.x;
    den += p.y;
  }
  out[v] = num / (den + 1e-8f);
}

extern "C" void kernel_launch(void* const* d_in, const int* in_sizes, int n_in,
                              void* d_out, int out_size, void* d_ws, size_t ws_size,
                              hipStream_t stream) {
  const float* bg = (const float*)d_in[0];
  const float* ed = (const float*)d_in[1];
  // d_in[2] context_mask: unused by reference
  const float* w1 = (const float*)d_in[3];
  const float* b1 = (const float*)d_in[4];
  const float* g1 = (const float*)d_in[5];
  const float* be1 = (const float*)d_in[6];
  const float* m1 = (const float*)d_in[7];
  const float* v1 = (const float*)d_in[8];
  const float* w2 = (const float*)d_in[9];
  const float* b2 = (const float*)d_in[10];
  const float* g2 = (const float*)d_in[11];
  const float* be2 = (const float*)d_in[12];
  const float* m2 = (const float*)d_in[13];
  const float* v2 = (const float*)d_in[14];
  const float* w3 = (const float*)d_in[15];
  const float* b3 = (const float*)d_in[16];
  const float* db = (const float*)d_in[17];
  const float* labels = (const float*)d_in[18];
  float* out = (float*)d_out;

  char* ws = (char*)d_ws;
  // Workspace layout (regions reused across pipeline stages; all dead-before-
  // overwrite by kernel order):
  //   A  (conv1 out, 2MB)  at 0          -- dead after conv2
  //   B  (conv2 out, 4MB)  at 2MB        -- dead after conv3
  //   Q  (latents,   1MB)  at 0          -- reuses A; live through knn2
  //   pk (pass1 top10, NC*1.31MB) at 1MB -- overlaps dead A-tail/B; dead after merge1
  //   T  (threshold, 128KB) after pk
  //   nd (pass2 partials, 2MB) at 1MB    -- reuses pk space
  const size_t off_A = 0;
  const size_t off_B = (size_t)16 * NVOX * 4;          // 2MB
  const size_t off_Q = 0;
  const size_t off_pk = (size_t)NVOX * 8 * 4;          // 1MB
  const size_t tbytes = (size_t)NVOX * 4;              // 128KB

  int NC = 4;  // pass-1 chunks (occupancy): largest of {16,8,4} that fits
  {
    size_t need16 = off_pk + (size_t)16 * NVOX * 10 * 4 + tbytes;
    size_t need8 = off_pk + (size_t)8 * NVOX * 10 * 4 + tbytes;
    if (ws_size >= need16) NC = 16;
    else if (ws_size >= need8) NC = 8;
  }
  const int NC2 = 8;  // pass-2 chunks (partials are additive, only 2MB)

  float* A = (float*)(ws + off_A);
  float* B = (float*)(ws + off_B);
  float* Q = (float*)(ws + off_Q);
  float* pk = (float*)(ws + off_pk);
  float* T = (float*)(ws + off_pk + (size_t)NC * NVOX * 10 * 4);
  float2* nd = (float2*)(ws + off_pk);  // reuses pk (pk dead after merge1)

  k_conv1<<<NVOX / 256, 256, 0, stream>>>(bg, ed, w1, b1, g1, be1, m1, v1, A);
  k_conv2<<<2 * (NVOX / 256), 256, 0, stream>>>(A, w2, b2, g2, be2, m2, v2, B);
  k_conv3<<<NVOX / 256, 256, 0, stream>>>(B, w3, b3, Q);
  k_knn1<<<NC * (NVOX / 256), 256, 0, stream>>>(Q, db, pk, NC);
  k_merge1<<<NVOX / 256, 256, 0, stream>>>(pk, T, NC);
  k_knn2<<<NC2 * (NVOX / 256), 256, 0, stream>>>(Q, db, T, labels, nd, NC2);
  k_out<<<NVOX / 256, 256, 0, stream>>>(nd, out, NC2);
}

// Round 3
// 189.153 us; speedup vs baseline: 1.3690x; 1.3690x over previous
//
#include <hip/hip_runtime.h>

#define ALPHA 10.0f
#define BN_EPS 1e-5f
#define NVOX 32768   // 32*32*32
#define MDB 4096
#define NC1 4        // phase-1 db chunks (4096/NC1 rows each)
#define NC2 4        // phase-2 db chunks
#define ROWS1 (MDB / NC1)
#define ROWS2 (MDB / NC2)

typedef __attribute__((ext_vector_type(8))) short short8;
typedef __attribute__((ext_vector_type(16))) float f32x16;

// ---------- 3-way bf16 split helpers ----------
__device__ __forceinline__ unsigned short bfr(float x) {
  unsigned u = __float_as_uint(x);
  return (unsigned short)((u + 0x7FFFu + ((u >> 16) & 1u)) >> 16);
}
__device__ __forceinline__ void split3(float x, unsigned short& h,
                                       unsigned short& m, unsigned short& l) {
  h = bfr(x);
  float fh = __uint_as_float((unsigned)h << 16);
  float x1 = x - fh;
  m = bfr(x1);
  float fm = __uint_as_float((unsigned)m << 16);
  l = bfr(x1 - fm);
}

// d2 tile: acc = (-2 db)·q  [hh+hm | mh+mm | lh+hl]  + dbdb + qq
// IDENTICAL instruction sequence in both kNN phases -> bit-identical d2.
__device__ __forceinline__ f32x16 d2_tile(short8 a1, short8 a2, short8 a3,
                                          short8 a4, short8 b1, short8 b3,
                                          short8 b4) {
  f32x16 acc = {};
  acc = __builtin_amdgcn_mfma_f32_32x32x16_bf16(a4, b4, acc, 0, 0, 0);
  acc = __builtin_amdgcn_mfma_f32_32x32x16_bf16(a3, b3, acc, 0, 0, 0);
  acc = __builtin_amdgcn_mfma_f32_32x32x16_bf16(a2, b1, acc, 0, 0, 0);
  acc = __builtin_amdgcn_mfma_f32_32x32x16_bf16(a1, b1, acc, 0, 0, 0);
  return acc;
}

__device__ __forceinline__ float fmin3(float a, float b, float c) {
  return fminf(fminf(a, b), c);
}

// Insert a PAIR of values into sorted-ascending d[0..9] (keep 10 smallest).
// d'[k] = min3(d[k], max(d[k-1],lo), max(d[k-2],hi)), descending k.
#define INSERT2(d, va, vb)                                              \
  do {                                                                  \
    float _lo = fminf((va), (vb)), _hi = fmaxf((va), (vb));             \
    _Pragma("unroll")                                                   \
    for (int _k = 9; _k >= 2; --_k)                                     \
      d[_k] = fmin3(d[_k], fmaxf(d[_k - 1], _lo), fmaxf(d[_k - 2], _hi)); \
    d[1] = fmin3(d[1], fmaxf(d[0], _lo), _hi);                          \
    d[0] = fminf(d[0], _lo);                                            \
  } while (0)

// ---------------- db prep: -2*db 3-way split + [dbdb,1] fragment ----------
__global__ __launch_bounds__(256) void k_dbprep(
    const float* __restrict__ db, unsigned short* __restrict__ DBH,
    unsigned short* __restrict__ DBM, unsigned short* __restrict__ DBL,
    unsigned short* __restrict__ DB4) {
  int j = blockIdx.x * 256 + threadIdx.x;
  float4 x0 = ((const float4*)(db + (size_t)j * 8))[0];
  float4 x1 = ((const float4*)(db + (size_t)j * 8))[1];
  float x[8] = {x0.x, x0.y, x0.z, x0.w, x1.x, x1.y, x1.z, x1.w};
  float ss = x[0] * x[0];
#pragma unroll
  for (int i = 1; i < 8; ++i) ss = fmaf(x[i], x[i], ss);
  short8 sh = {}, sm = {}, sl = {};
#pragma unroll
  for (int i = 0; i < 8; ++i) {
    unsigned short h, m, l;
    split3(-2.f * x[i], h, m, l);
    sh[i] = (short)h; sm[i] = (short)m; sl[i] = (short)l;
  }
  unsigned short dh, dm, dl;
  split3(ss, dh, dm, dl);
  short8 s4 = {};
  s4[0] = (short)dh; s4[1] = (short)dm; s4[2] = (short)dl;
  s4[3] = (short)0x3F80; s4[4] = (short)0x3F80; s4[5] = (short)0x3F80;
  *(short8*)(DBH + (size_t)j * 8) = sh;
  *(short8*)(DBM + (size_t)j * 8) = sm;
  *(short8*)(DBL + (size_t)j * 8) = sl;
  *(short8*)(DB4 + (size_t)j * 8) = s4;
}

// ---------------- conv1: 2->16, k3, pad1, +BN+ReLU ----------------
__global__ __launch_bounds__(256) void k_conv1(
    const float* __restrict__ bg, const float* __restrict__ ed,
    const float* __restrict__ w1, const float* __restrict__ b1,
    const float* __restrict__ g1, const float* __restrict__ be1,
    const float* __restrict__ m1, const float* __restrict__ v1,
    float* __restrict__ A) {
  __shared__ float wT[54 * 16];
  __shared__ float sc[16], sh[16];
  int t = threadIdx.x;
  for (int i = t; i < 864; i += 256) {
    int o = i & 15, r = i >> 4;
    wT[i] = w1[o * 54 + r];
  }
  if (t < 16) {
    float s = g1[t] * rsqrtf(v1[t] + BN_EPS);
    sc[t] = s;
    sh[t] = (b1[t] - m1[t]) * s + be1[t];
  }
  __syncthreads();
  int v = blockIdx.x * 256 + t;
  int x = v & 31, y = (v >> 5) & 31, z = v >> 10;
  float acc[16];
#pragma unroll
  for (int o = 0; o < 16; ++o) acc[o] = 0.f;
#pragma unroll 1
  for (int k = 0; k < 27; ++k) {
    int dz = k / 9 - 1, dy = (k / 3) % 3 - 1, dx = k % 3 - 1;
    int zz = z + dz, yy = y + dy, xx = x + dx;
    bool inb = (unsigned)zz < 32u && (unsigned)yy < 32u && (unsigned)xx < 32u;
    int vv = zz * 1024 + yy * 32 + xx;
#pragma unroll
    for (int c = 0; c < 2; ++c) {
      const float* in = c ? ed : bg;
      float val = inb ? in[vv] : 0.f;
      const float4* wp = (const float4*)&wT[(c * 27 + k) * 16];
      float4 wa = wp[0], wb = wp[1], wc = wp[2], wd = wp[3];
      acc[0] = fmaf(val, wa.x, acc[0]);  acc[1] = fmaf(val, wa.y, acc[1]);
      acc[2] = fmaf(val, wa.z, acc[2]);  acc[3] = fmaf(val, wa.w, acc[3]);
      acc[4] = fmaf(val, wb.x, acc[4]);  acc[5] = fmaf(val, wb.y, acc[5]);
      acc[6] = fmaf(val, wb.z, acc[6]);  acc[7] = fmaf(val, wb.w, acc[7]);
      acc[8] = fmaf(val, wc.x, acc[8]);  acc[9] = fmaf(val, wc.y, acc[9]);
      acc[10] = fmaf(val, wc.z, acc[10]); acc[11] = fmaf(val, wc.w, acc[11]);
      acc[12] = fmaf(val, wd.x, acc[12]); acc[13] = fmaf(val, wd.y, acc[13]);
      acc[14] = fmaf(val, wd.z, acc[14]); acc[15] = fmaf(val, wd.w, acc[15]);
    }
  }
#pragma unroll
  for (int o = 0; o < 16; ++o) {
    float y2 = fmaf(acc[o], sc[o], sh[o]);
    A[o * NVOX + v] = y2 > 0.f ? y2 : 0.f;
  }
}

// ---------------- conv2: 16->32, k3, pad1, +BN+ReLU ----------------
__global__ __launch_bounds__(256) void k_conv2(
    const float* __restrict__ A, const float* __restrict__ w2,
    const float* __restrict__ b2, const float* __restrict__ g2,
    const float* __restrict__ be2, const float* __restrict__ m2,
    const float* __restrict__ v2, float* __restrict__ B) {
  __shared__ float wT[432 * 16];
  __shared__ float sc[16], sh[16];
  int t = threadIdx.x;
  int h = blockIdx.x >> 7;
  int vb = blockIdx.x & 127;
  for (int i = t; i < 6912; i += 256) {
    int o = i & 15, r = i >> 4;
    wT[i] = w2[(h * 16 + o) * 432 + r];
  }
  if (t < 16) {
    int o = h * 16 + t;
    float s = g2[o] * rsqrtf(v2[o] + BN_EPS);
    sc[t] = s;
    sh[t] = (b2[o] - m2[o]) * s + be2[o];
  }
  __syncthreads();
  int v = vb * 256 + t;
  int x = v & 31, y = (v >> 5) & 31, z = v >> 10;
  float acc[16];
#pragma unroll
  for (int o = 0; o < 16; ++o) acc[o] = 0.f;
#pragma unroll 1
  for (int k = 0; k < 27; ++k) {
    int dz = k / 9 - 1, dy = (k / 3) % 3 - 1, dx = k % 3 - 1;
    int zz = z + dz, yy = y + dy, xx = x + dx;
    bool inb = (unsigned)zz < 32u && (unsigned)yy < 32u && (unsigned)xx < 32u;
    int vv = zz * 1024 + yy * 32 + xx;
#pragma unroll
    for (int ci = 0; ci < 16; ++ci) {
      float val = inb ? A[ci * NVOX + vv] : 0.f;
      const float4* wp = (const float4*)&wT[(ci * 27 + k) * 16];
      float4 wa = wp[0], wb = wp[1], wc = wp[2], wd = wp[3];
      acc[0] = fmaf(val, wa.x, acc[0]);  acc[1] = fmaf(val, wa.y, acc[1]);
      acc[2] = fmaf(val, wa.z, acc[2]);  acc[3] = fmaf(val, wa.w, acc[3]);
      acc[4] = fmaf(val, wb.x, acc[4]);  acc[5] = fmaf(val, wb.y, acc[5]);
      acc[6] = fmaf(val, wb.z, acc[6]);  acc[7] = fmaf(val, wb.w, acc[7]);
      acc[8] = fmaf(val, wc.x, acc[8]);  acc[9] = fmaf(val, wc.y, acc[9]);
      acc[10] = fmaf(val, wc.z, acc[10]); acc[11] = fmaf(val, wc.w, acc[11]);
      acc[12] = fmaf(val, wd.x, acc[12]); acc[13] = fmaf(val, wd.y, acc[13]);
      acc[14] = fmaf(val, wd.z, acc[14]); acc[15] = fmaf(val, wd.w, acc[15]);
    }
  }
#pragma unroll
  for (int o = 0; o < 16; ++o) {
    float y2 = fmaf(acc[o], sc[o], sh[o]);
    B[(h * 16 + o) * NVOX + v] = y2 > 0.f ? y2 : 0.f;
  }
}

// ---- conv3 (1x1x1) 32->8 + L2 normalize + emit bf16 query fragments ----
__global__ __launch_bounds__(256) void k_conv3q(
    const float* __restrict__ B, const float* __restrict__ w3,
    const float* __restrict__ b3, unsigned short* __restrict__ QH,
    unsigned short* __restrict__ QM, unsigned short* __restrict__ QL,
    unsigned short* __restrict__ Q4) {
  __shared__ float wT[32 * 8];
  __shared__ float bL[8];
  int t = threadIdx.x;
  {
    int o = t & 7, ci = t >> 3;
    wT[t] = w3[o * 32 + ci];
  }
  if (t < 8) bL[t] = b3[t];
  __syncthreads();
  int v = blockIdx.x * 256 + t;
  float lat[8];
#pragma unroll
  for (int o = 0; o < 8; ++o) lat[o] = bL[o];
#pragma unroll 4
  for (int ci = 0; ci < 32; ++ci) {
    float val = B[ci * NVOX + v];
    const float4* wp = (const float4*)&wT[ci * 8];
    float4 wa = wp[0], wb = wp[1];
    lat[0] = fmaf(val, wa.x, lat[0]); lat[1] = fmaf(val, wa.y, lat[1]);
    lat[2] = fmaf(val, wa.z, lat[2]); lat[3] = fmaf(val, wa.w, lat[3]);
    lat[4] = fmaf(val, wb.x, lat[4]); lat[5] = fmaf(val, wb.y, lat[5]);
    lat[6] = fmaf(val, wb.z, lat[6]); lat[7] = fmaf(val, wb.w, lat[7]);
  }
  float n2 = 0.f;
#pragma unroll
  for (int o = 0; o < 8; ++o) n2 = fmaf(lat[o], lat[o], n2);
  float inv = 1.f / fmaxf(sqrtf(n2), 1e-12f);
  float q[8];
#pragma unroll
  for (int o = 0; o < 8; ++o) q[o] = lat[o] * inv;
  float qq = q[0] * q[0];
#pragma unroll
  for (int o = 1; o < 8; ++o) qq = fmaf(q[o], q[o], qq);
  short8 sh = {}, sm = {}, sl = {};
#pragma unroll
  for (int o = 0; o < 8; ++o) {
    unsigned short h, m, l;
    split3(q[o], h, m, l);
    sh[o] = (short)h; sm[o] = (short)m; sl[o] = (short)l;
  }
  unsigned short qh, qm, ql;
  split3(qq, qh, qm, ql);
  short8 s4 = {};
  s4[0] = (short)0x3F80; s4[1] = (short)0x3F80; s4[2] = (short)0x3F80;
  s4[3] = (short)qh; s4[4] = (short)qm; s4[5] = (short)ql;
  *(short8*)(QH + (size_t)v * 8) = sh;
  *(short8*)(QM + (size_t)v * 8) = sm;
  *(short8*)(QL + (size_t)v * 8) = sl;
  *(short8*)(Q4 + (size_t)v * 8) = s4;
}

// ------- kNN phase 1 (MFMA): per-(query,chunk) top-10 distances -------
__global__ __launch_bounds__(256) void k_knn1(
    const unsigned short* __restrict__ QH, const unsigned short* __restrict__ QM,
    const unsigned short* __restrict__ QL, const unsigned short* __restrict__ Q4,
    const unsigned short* __restrict__ DBH, const unsigned short* __restrict__ DBM,
    const unsigned short* __restrict__ DBL, const unsigned short* __restrict__ DB4,
    float* __restrict__ pk) {
  int t = threadIdx.x, w = t >> 6, l = t & 63;
  int lo32 = l & 31, hi = l >> 5;
  int c = blockIdx.x >> 8;          // chunk (NC1*256 blocks total)
  int b = blockIdx.x & 255;
  int qt = b * 4 + w;               // query tile 0..1023
  int q = qt * 32 + lo32;
  short8 zz = {};
  short8 b1 = *(const short8*)((hi ? QM : QH) + (size_t)q * 8);
  short8 b3 = *(const short8*)((hi ? QL : QH) + (size_t)q * 8);
  short8 b4v = *(const short8*)(Q4 + (size_t)q * 8);
  short8 b4 = hi ? zz : b4v;
  float d[10];
#pragma unroll
  for (int k = 0; k < 10; ++k) d[k] = 3.4e38f;
  int r0 = c * ROWS1;
#pragma unroll 2
  for (int tt = 0; tt < ROWS1 / 32; ++tt) {
    int r = r0 + tt * 32 + lo32;
    short8 a1 = *(const short8*)(DBH + (size_t)r * 8);
    short8 a2 = *(const short8*)(DBM + (size_t)r * 8);
    short8 a3 = *(const short8*)((hi ? DBH : DBL) + (size_t)r * 8);
    short8 a4 = *(const short8*)(DB4 + (size_t)r * 8);
    f32x16 acc = d2_tile(a1, a2, a3, a4, b1, b3, b4);
#pragma unroll
    for (int p = 0; p < 8; ++p) INSERT2(d, acc[2 * p], acc[2 * p + 1]);
  }
  // merge the two lane-halves (complementary row sets, same query)
  float e[10];
#pragma unroll
  for (int k = 0; k < 10; ++k) e[k] = __shfl_xor(d[k], 32);
#pragma unroll
  for (int k = 0; k < 10; k += 2) INSERT2(d, e[k], e[k + 1]);
  if (l < 32) {
#pragma unroll
    for (int k = 0; k < 10; ++k) pk[((size_t)c * 10 + k) * NVOX + q] = d[k];
  }
}

// -------- merge partial top-10s -> exact 10th-smallest threshold --------
__global__ __launch_bounds__(256) void k_merge1(
    const float* __restrict__ pk, float* __restrict__ T) {
  int v = blockIdx.x * 256 + threadIdx.x;
  float d[10];
#pragma unroll
  for (int k = 0; k < 10; ++k) d[k] = 3.4e38f;
#pragma unroll
  for (int c = 0; c < NC1; ++c) {
#pragma unroll
    for (int k2 = 0; k2 < 10; k2 += 2) {
      float va = pk[((size_t)c * 10 + k2) * NVOX + v];
      float vb = pk[((size_t)c * 10 + k2 + 1) * NVOX + v];
      INSERT2(d, va, vb);
    }
  }
  T[v] = d[9];
}

// ------- kNN phase 2 (MFMA): exp-weighted label sums for d2 <= T -------
__global__ __launch_bounds__(256) void k_knn2(
    const unsigned short* __restrict__ QH, const unsigned short* __restrict__ QM,
    const unsigned short* __restrict__ QL, const unsigned short* __restrict__ Q4,
    const unsigned short* __restrict__ DBH, const unsigned short* __restrict__ DBM,
    const unsigned short* __restrict__ DBL, const unsigned short* __restrict__ DB4,
    const float* __restrict__ T, const float* __restrict__ labels,
    float2* __restrict__ nd) {
  __shared__ float lab[ROWS2];
  int t = threadIdx.x, w = t >> 6, l = t & 63;
  int lo32 = l & 31, hi = l >> 5;
  int c = blockIdx.x >> 8;
  int b = blockIdx.x & 255;
  int qt = b * 4 + w;
  int q = qt * 32 + lo32;
  ((float4*)lab)[t] = ((const float4*)(labels + (size_t)c * ROWS2))[t];
  __syncthreads();
  short8 zz = {};
  short8 b1 = *(const short8*)((hi ? QM : QH) + (size_t)q * 8);
  short8 b3 = *(const short8*)((hi ? QL : QH) + (size_t)q * 8);
  short8 b4v = *(const short8*)(Q4 + (size_t)q * 8);
  short8 b4 = hi ? zz : b4v;
  float Tv = T[q];
  const float C2 = -14.4269504088896340736f;  // -ALPHA * log2(e)
  float num = 0.f, den = 0.f;
  int r0 = c * ROWS2;
#pragma unroll 2
  for (int tt = 0; tt < ROWS2 / 32; ++tt) {
    int r = r0 + tt * 32 + lo32;
    short8 a1 = *(const short8*)(DBH + (size_t)r * 8);
    short8 a2 = *(const short8*)(DBM + (size_t)r * 8);
    short8 a3 = *(const short8*)((hi ? DBH : DBL) + (size_t)r * 8);
    short8 a4 = *(const short8*)(DB4 + (size_t)r * 8);
    f32x16 acc = d2_tile(a1, a2, a3, a4, b1, b3, b4);
#pragma unroll
    for (int i = 0; i < 16; ++i) {
      float d2v = acc[i];
      float lb = lab[tt * 32 + 4 * hi + (i & 3) + 8 * (i >> 2)];
      float arg = (d2v <= Tv) ? d2v * C2 : -1.0e4f;
      float wgt = exp2f(arg);
      num = fmaf(wgt, lb, num);
      den += wgt;
    }
  }
  num += __shfl_xor(num, 32);
  den += __shfl_xor(den, 32);
  if (l < 32) nd[(size_t)c * NVOX + q] = make_float2(num, den);
}

// ---------------- final reduction over phase-2 chunks ----------------
__global__ __launch_bounds__(256) void k_out(
    const float2* __restrict__ nd_in, float* __restrict__ out) {
  int v = blockIdx.x * 256 + threadIdx.x;
  float num = 0.f, den = 0.f;
#pragma unroll
  for (int c = 0; c < NC2; ++c) {
    float2 p = nd_in[(size_t)c * NVOX + v];
    num += p.x;
    den += p.y;
  }
  out[v] = num / (den + 1e-8f);
}

extern "C" void kernel_launch(void* const* d_in, const int* in_sizes, int n_in,
                              void* d_out, int out_size, void* d_ws, size_t ws_size,
                              hipStream_t stream) {
  const float* bg = (const float*)d_in[0];
  const float* ed = (const float*)d_in[1];
  const float* w1 = (const float*)d_in[3];
  const float* b1 = (const float*)d_in[4];
  const float* g1 = (const float*)d_in[5];
  const float* be1 = (const float*)d_in[6];
  const float* m1 = (const float*)d_in[7];
  const float* v1 = (const float*)d_in[8];
  const float* w2 = (const float*)d_in[9];
  const float* b2 = (const float*)d_in[10];
  const float* g2 = (const float*)d_in[11];
  const float* be2 = (const float*)d_in[12];
  const float* m2 = (const float*)d_in[13];
  const float* v2 = (const float*)d_in[14];
  const float* w3 = (const float*)d_in[15];
  const float* b3 = (const float*)d_in[16];
  const float* db = (const float*)d_in[17];
  const float* labels = (const float*)d_in[18];
  float* out = (float*)d_out;

  char* ws = (char*)d_ws;
  // layout (MB offsets; regions reused when dead):
  //  [0,2)    A (conv1 out) -> later QH/QM/QL/Q4 (4x512KB, written by conv3q)
  //  [2,6)    B (conv2 out)
  //  [6,6.25) DBH/DBM/DBL/DB4 (4x64KB)
  //  [6.25,11.5) pk (NC1*10*NVOX*4 = 5.25MB)
  //  [11.5,...) T (128KB), nd (NC2*NVOX*8 = 1MB)
  const size_t MB = 1024 * 1024;
  float* A = (float*)(ws + 0);
  float* B = (float*)(ws + 2 * MB);
  unsigned short* QH = (unsigned short*)(ws + 0);
  unsigned short* QM = QH + (size_t)NVOX * 8;
  unsigned short* QL = QM + (size_t)NVOX * 8;
  unsigned short* Q4 = QL + (size_t)NVOX * 8;
  unsigned short* DBH = (unsigned short*)(ws + 6 * MB);
  unsigned short* DBM = DBH + (size_t)MDB * 8;
  unsigned short* DBL = DBM + (size_t)MDB * 8;
  unsigned short* DB4 = DBL + (size_t)MDB * 8;
  float* pk = (float*)(ws + 6 * MB + 256 * 1024);
  float* T = (float*)(ws + 6 * MB + 256 * 1024 + (size_t)NC1 * 10 * NVOX * 4);
  float2* nd = (float2*)((char*)T + (size_t)NVOX * 4);

  k_dbprep<<<MDB / 256, 256, 0, stream>>>(db, DBH, DBM, DBL, DB4);
  k_conv1<<<NVOX / 256, 256, 0, stream>>>(bg, ed, w1, b1, g1, be1, m1, v1, A);
  k_conv2<<<2 * (NVOX / 256), 256, 0, stream>>>(A, w2, b2, g2, be2, m2, v2, B);
  k_conv3q<<<NVOX / 256, 256, 0, stream>>>(B, w3, b3, QH, QM, QL, Q4);
  k_knn1<<<NC1 * 256, 256, 0, stream>>>(QH, QM, QL, Q4, DBH, DBM, DBL, DB4, pk);
  k_merge1<<<NVOX / 256, 256, 0, stream>>>(pk, T);
  k_knn2<<<NC2 * 256, 256, 0, stream>>>(QH, QM, QL, Q4, DBH, DBM, DBL, DB4, T,
                                        labels, nd);
  k_out<<<NVOX / 256, 256, 0, stream>>>(nd, out);
}

// Round 4
// 180.039 us; speedup vs baseline: 1.4383x; 1.0506x over previous
//
#include <hip/hip_runtime.h>

#define ALPHA 10.0f
#define BN_EPS 1e-5f
#define NVOX 32768   // 32*32*32
#define MDB 4096
#define NC2 8        // phase-2 db chunks (fixed; partials additive)

typedef __attribute__((ext_vector_type(8))) short short8;
typedef __attribute__((ext_vector_type(16))) float f32x16;

// ---------- 3-way bf16 split helpers ----------
__device__ __forceinline__ unsigned short bfr(float x) {
  unsigned u = __float_as_uint(x);
  return (unsigned short)((u + 0x7FFFu + ((u >> 16) & 1u)) >> 16);
}
__device__ __forceinline__ void split3(float x, unsigned short& h,
                                       unsigned short& m, unsigned short& l) {
  h = bfr(x);
  float fh = __uint_as_float((unsigned)h << 16);
  float x1 = x - fh;
  m = bfr(x1);
  float fm = __uint_as_float((unsigned)m << 16);
  l = bfr(x1 - fm);
}

// d2 tile: acc = (-2 db)·q  [hh+hm | mh+mm | lh+hl]  + dbdb + qq
// IDENTICAL instruction sequence in both kNN phases -> bit-identical d2.
__device__ __forceinline__ f32x16 d2_tile(short8 a1, short8 a2, short8 a3,
                                          short8 a4, short8 b1, short8 b3,
                                          short8 b4) {
  f32x16 acc = {};
  acc = __builtin_amdgcn_mfma_f32_32x32x16_bf16(a4, b4, acc, 0, 0, 0);
  acc = __builtin_amdgcn_mfma_f32_32x32x16_bf16(a3, b3, acc, 0, 0, 0);
  acc = __builtin_amdgcn_mfma_f32_32x32x16_bf16(a2, b1, acc, 0, 0, 0);
  acc = __builtin_amdgcn_mfma_f32_32x32x16_bf16(a1, b1, acc, 0, 0, 0);
  return acc;
}

__device__ __forceinline__ float fmin3(float a, float b, float c) {
  return fminf(fminf(a, b), c);  // fuses to v_min3_f32
}

// Insert a PAIR of values into sorted-ascending d[0..9] (keep 10 smallest).
#define INSERT2(d, va, vb)                                              \
  do {                                                                  \
    float _lo = fminf((va), (vb)), _hi = fmaxf((va), (vb));             \
    _Pragma("unroll")                                                   \
    for (int _k = 9; _k >= 2; --_k)                                     \
      d[_k] = fmin3(d[_k], fmaxf(d[_k - 1], _lo), fmaxf(d[_k - 2], _hi)); \
    d[1] = fmin3(d[1], fmaxf(d[0], _lo), _hi);                          \
    d[0] = fminf(d[0], _lo);                                            \
  } while (0)

// ------- conv1 (blocks 0..127) + db/label prep (blocks 128..143) -------
__global__ __launch_bounds__(256) void k_conv1p(
    const float* __restrict__ bg, const float* __restrict__ ed,
    const float* __restrict__ w1, const float* __restrict__ b1,
    const float* __restrict__ g1, const float* __restrict__ be1,
    const float* __restrict__ m1, const float* __restrict__ v1,
    float* __restrict__ A, const float* __restrict__ db,
    const float* __restrict__ labels, unsigned short* __restrict__ DBH,
    unsigned short* __restrict__ DBM, unsigned short* __restrict__ DBL,
    unsigned short* __restrict__ DB4, unsigned* __restrict__ LBL2) {
  int t = threadIdx.x;
  if (blockIdx.x >= 128) {  // ---- prep path ----
    int j = (blockIdx.x - 128) * 256 + t;
    float4 x0 = ((const float4*)(db + (size_t)j * 8))[0];
    float4 x1 = ((const float4*)(db + (size_t)j * 8))[1];
    float x[8] = {x0.x, x0.y, x0.z, x0.w, x1.x, x1.y, x1.z, x1.w};
    float ss = x[0] * x[0];
#pragma unroll
    for (int i = 1; i < 8; ++i) ss = fmaf(x[i], x[i], ss);
    short8 sh = {}, sm = {}, sl = {};
#pragma unroll
    for (int i = 0; i < 8; ++i) {
      unsigned short h, m, l;
      split3(-2.f * x[i], h, m, l);
      sh[i] = (short)h; sm[i] = (short)m; sl[i] = (short)l;
    }
    unsigned short dh, dm, dl;
    split3(ss, dh, dm, dl);
    short8 s4 = {};
    s4[0] = (short)dh; s4[1] = (short)dm; s4[2] = (short)dl;
    s4[3] = (short)0x3F80; s4[4] = (short)0x3F80; s4[5] = (short)0x3F80;
    *(short8*)(DBH + (size_t)j * 8) = sh;
    *(short8*)(DBM + (size_t)j * 8) = sm;
    *(short8*)(DBL + (size_t)j * 8) = sl;
    *(short8*)(DB4 + (size_t)j * 8) = s4;
    float lb = labels[j];
    unsigned short lh = bfr(lb);
    float lf = __uint_as_float((unsigned)lh << 16);
    unsigned short ll = bfr(lb - lf);
    LBL2[j] = (unsigned)lh | ((unsigned)ll << 16);
    return;
  }
  // ---- conv1 path ----
  __shared__ float wT[54 * 16];
  __shared__ float sc[16], shs[16];
  for (int i = t; i < 864; i += 256) {
    int o = i & 15, r = i >> 4;
    wT[i] = w1[o * 54 + r];
  }
  if (t < 16) {
    float s = g1[t] * rsqrtf(v1[t] + BN_EPS);
    sc[t] = s;
    shs[t] = (b1[t] - m1[t]) * s + be1[t];
  }
  __syncthreads();
  int v = blockIdx.x * 256 + t;
  int x = v & 31, y = (v >> 5) & 31, z = v >> 10;
  float acc[16];
#pragma unroll
  for (int o = 0; o < 16; ++o) acc[o] = 0.f;
#pragma unroll 1
  for (int k = 0; k < 27; ++k) {
    int dz = k / 9 - 1, dy = (k / 3) % 3 - 1, dx = k % 3 - 1;
    int zz = z + dz, yy = y + dy, xx = x + dx;
    bool inb = (unsigned)zz < 32u && (unsigned)yy < 32u && (unsigned)xx < 32u;
    int vv = zz * 1024 + yy * 32 + xx;
#pragma unroll
    for (int c = 0; c < 2; ++c) {
      const float* in = c ? ed : bg;
      float val = inb ? in[vv] : 0.f;
      const float4* wp = (const float4*)&wT[(c * 27 + k) * 16];
      float4 wa = wp[0], wb = wp[1], wc = wp[2], wd = wp[3];
      acc[0] = fmaf(val, wa.x, acc[0]);  acc[1] = fmaf(val, wa.y, acc[1]);
      acc[2] = fmaf(val, wa.z, acc[2]);  acc[3] = fmaf(val, wa.w, acc[3]);
      acc[4] = fmaf(val, wb.x, acc[4]);  acc[5] = fmaf(val, wb.y, acc[5]);
      acc[6] = fmaf(val, wb.z, acc[6]);  acc[7] = fmaf(val, wb.w, acc[7]);
      acc[8] = fmaf(val, wc.x, acc[8]);  acc[9] = fmaf(val, wc.y, acc[9]);
      acc[10] = fmaf(val, wc.z, acc[10]); acc[11] = fmaf(val, wc.w, acc[11]);
      acc[12] = fmaf(val, wd.x, acc[12]); acc[13] = fmaf(val, wd.y, acc[13]);
      acc[14] = fmaf(val, wd.z, acc[14]); acc[15] = fmaf(val, wd.w, acc[15]);
    }
  }
#pragma unroll
  for (int o = 0; o < 16; ++o) {
    float y2 = fmaf(acc[o], sc[o], shs[o]);
    A[o * NVOX + v] = y2 > 0.f ? y2 : 0.f;
  }
}

// -------- conv2: 16->32, k3, pad1, +BN+ReLU; 8 out-ch per block-group -----
__global__ __launch_bounds__(256) void k_conv2(
    const float* __restrict__ A, const float* __restrict__ w2,
    const float* __restrict__ b2, const float* __restrict__ g2,
    const float* __restrict__ be2, const float* __restrict__ m2,
    const float* __restrict__ v2, float* __restrict__ B) {
  __shared__ float wT[432 * 8];  // [ci*27+kk][o8]
  __shared__ float sc[8], shs[8];
  int t = threadIdx.x;
  int og = blockIdx.x >> 7;  // 0..3 -> 8 output channels each
  int vb = blockIdx.x & 127;
  for (int i = t; i < 3456; i += 256) {
    int o = i & 7, r = i >> 3;  // r = ci*27+kk
    wT[i] = w2[(og * 8 + o) * 432 + r];
  }
  if (t < 8) {
    int o = og * 8 + t;
    float s = g2[o] * rsqrtf(v2[o] + BN_EPS);
    sc[t] = s;
    shs[t] = (b2[o] - m2[o]) * s + be2[o];
  }
  __syncthreads();
  int v = vb * 256 + t;
  int x = v & 31, y = (v >> 5) & 31, z = v >> 10;
  float acc[8];
#pragma unroll
  for (int o = 0; o < 8; ++o) acc[o] = 0.f;
#pragma unroll 1
  for (int k = 0; k < 27; ++k) {
    int dz = k / 9 - 1, dy = (k / 3) % 3 - 1, dx = k % 3 - 1;
    int zz = z + dz, yy = y + dy, xx = x + dx;
    bool inb = (unsigned)zz < 32u && (unsigned)yy < 32u && (unsigned)xx < 32u;
    int vv = zz * 1024 + yy * 32 + xx;
#pragma unroll
    for (int ci = 0; ci < 16; ++ci) {
      float val = inb ? A[ci * NVOX + vv] : 0.f;
      const float4* wp = (const float4*)&wT[(ci * 27 + k) * 8];
      float4 wa = wp[0], wb = wp[1];
      acc[0] = fmaf(val, wa.x, acc[0]); acc[1] = fmaf(val, wa.y, acc[1]);
      acc[2] = fmaf(val, wa.z, acc[2]); acc[3] = fmaf(val, wa.w, acc[3]);
      acc[4] = fmaf(val, wb.x, acc[4]); acc[5] = fmaf(val, wb.y, acc[5]);
      acc[6] = fmaf(val, wb.z, acc[6]); acc[7] = fmaf(val, wb.w, acc[7]);
    }
  }
#pragma unroll
  for (int o = 0; o < 8; ++o) {
    float y2 = fmaf(acc[o], sc[o], shs[o]);
    B[(og * 8 + o) * NVOX + v] = y2 > 0.f ? y2 : 0.f;
  }
}

// ---- conv3 (1x1x1) 32->8 + L2 normalize + emit bf16 query fragments ----
__global__ __launch_bounds__(256) void k_conv3q(
    const float* __restrict__ B, const float* __restrict__ w3,
    const float* __restrict__ b3, unsigned short* __restrict__ QH,
    unsigned short* __restrict__ QM, unsigned short* __restrict__ QL,
    unsigned short* __restrict__ Q4) {
  __shared__ float wT[32 * 8];
  __shared__ float bL[8];
  int t = threadIdx.x;
  {
    int o = t & 7, ci = t >> 3;
    wT[t] = w3[o * 32 + ci];
  }
  if (t < 8) bL[t] = b3[t];
  __syncthreads();
  int v = blockIdx.x * 256 + t;
  float lat[8];
#pragma unroll
  for (int o = 0; o < 8; ++o) lat[o] = bL[o];
#pragma unroll 4
  for (int ci = 0; ci < 32; ++ci) {
    float val = B[ci * NVOX + v];
    const float4* wp = (const float4*)&wT[ci * 8];
    float4 wa = wp[0], wb = wp[1];
    lat[0] = fmaf(val, wa.x, lat[0]); lat[1] = fmaf(val, wa.y, lat[1]);
    lat[2] = fmaf(val, wa.z, lat[2]); lat[3] = fmaf(val, wa.w, lat[3]);
    lat[4] = fmaf(val, wb.x, lat[4]); lat[5] = fmaf(val, wb.y, lat[5]);
    lat[6] = fmaf(val, wb.z, lat[6]); lat[7] = fmaf(val, wb.w, lat[7]);
  }
  float n2 = 0.f;
#pragma unroll
  for (int o = 0; o < 8; ++o) n2 = fmaf(lat[o], lat[o], n2);
  float inv = 1.f / fmaxf(sqrtf(n2), 1e-12f);
  float q[8];
#pragma unroll
  for (int o = 0; o < 8; ++o) q[o] = lat[o] * inv;
  float qq = q[0] * q[0];
#pragma unroll
  for (int o = 1; o < 8; ++o) qq = fmaf(q[o], q[o], qq);
  short8 sh = {}, sm = {}, sl = {};
#pragma unroll
  for (int o = 0; o < 8; ++o) {
    unsigned short h, m, l;
    split3(q[o], h, m, l);
    sh[o] = (short)h; sm[o] = (short)m; sl[o] = (short)l;
  }
  unsigned short qh, qm, ql;
  split3(qq, qh, qm, ql);
  short8 s4 = {};
  s4[0] = (short)0x3F80; s4[1] = (short)0x3F80; s4[2] = (short)0x3F80;
  s4[3] = (short)qh; s4[4] = (short)qm; s4[5] = (short)ql;
  *(short8*)(QH + (size_t)v * 8) = sh;
  *(short8*)(QM + (size_t)v * 8) = sm;
  *(short8*)(QL + (size_t)v * 8) = sl;
  *(short8*)(Q4 + (size_t)v * 8) = s4;
}

// ------- kNN phase 1 (MFMA): per-(query,chunk) top-10 distances -------
__global__ __launch_bounds__(256) void k_knn1(
    const unsigned short* __restrict__ QH, const unsigned short* __restrict__ QM,
    const unsigned short* __restrict__ QL, const unsigned short* __restrict__ Q4,
    const unsigned short* __restrict__ DBH, const unsigned short* __restrict__ DBM,
    const unsigned short* __restrict__ DBL, const unsigned short* __restrict__ DB4,
    float* __restrict__ pk, int rows1) {
  int t = threadIdx.x, w = t >> 6, l = t & 63;
  int lo32 = l & 31, hi = l >> 5;
  int c = blockIdx.x >> 8;  // chunk
  int b = blockIdx.x & 255;
  int qt = b * 4 + w;
  int q = qt * 32 + lo32;
  short8 zz = {};
  short8 b1 = *(const short8*)((hi ? QM : QH) + (size_t)q * 8);
  short8 b3 = *(const short8*)((hi ? QL : QH) + (size_t)q * 8);
  short8 b4v = *(const short8*)(Q4 + (size_t)q * 8);
  short8 b4 = hi ? zz : b4v;
  float d[10];
#pragma unroll
  for (int k = 0; k < 10; ++k) d[k] = 3.4e38f;
  int r0 = c * rows1;
  int ntiles = rows1 >> 5;
#pragma unroll 2
  for (int tt = 0; tt < ntiles; ++tt) {
    int r = r0 + tt * 32 + lo32;
    short8 a1 = *(const short8*)(DBH + (size_t)r * 8);
    short8 a2 = *(const short8*)(DBM + (size_t)r * 8);
    short8 a3 = *(const short8*)((hi ? DBH : DBL) + (size_t)r * 8);
    short8 a4 = *(const short8*)(DB4 + (size_t)r * 8);
    f32x16 acc = d2_tile(a1, a2, a3, a4, b1, b3, b4);
#pragma unroll
    for (int p = 0; p < 8; ++p) INSERT2(d, acc[2 * p], acc[2 * p + 1]);
  }
  float e[10];
#pragma unroll
  for (int k = 0; k < 10; ++k) e[k] = __shfl_xor(d[k], 32);
#pragma unroll
  for (int k = 0; k < 10; k += 2) INSERT2(d, e[k], e[k + 1]);
  if (l < 32) {
#pragma unroll
    for (int k = 0; k < 10; ++k) pk[((size_t)c * 10 + k) * NVOX + q] = d[k];
  }
}

// -------- merge partial top-10s -> exact 10th-smallest threshold --------
__global__ __launch_bounds__(256) void k_merge1(
    const float* __restrict__ pk, float* __restrict__ T, int nc) {
  int v = blockIdx.x * 256 + threadIdx.x;
  float d[10];
#pragma unroll
  for (int k = 0; k < 10; ++k) d[k] = 3.4e38f;
#pragma unroll 1
  for (int c = 0; c < nc; ++c) {
#pragma unroll
    for (int k2 = 0; k2 < 10; k2 += 2) {
      float va = pk[((size_t)c * 10 + k2) * NVOX + v];
      float vb = pk[((size_t)c * 10 + k2 + 1) * NVOX + v];
      INSERT2(d, va, vb);
    }
  }
  T[v] = d[9];
}

// ------- kNN phase 2 (MFMA): exp-weighted label sums for d2 <= T -------
// Labels delivered via one extra MFMA: accL[i] = lbl[row(i)] (2-split exact).
__global__ __launch_bounds__(256) void k_knn2(
    const unsigned short* __restrict__ QH, const unsigned short* __restrict__ QM,
    const unsigned short* __restrict__ QL, const unsigned short* __restrict__ Q4,
    const unsigned short* __restrict__ DBH, const unsigned short* __restrict__ DBM,
    const unsigned short* __restrict__ DBL, const unsigned short* __restrict__ DB4,
    const unsigned* __restrict__ LBL2, const float* __restrict__ T,
    float2* __restrict__ nd) {
  int t = threadIdx.x, w = t >> 6, l = t & 63;
  int lo32 = l & 31, hi = l >> 5;
  int c = blockIdx.x >> 8;
  int b = blockIdx.x & 255;
  int qt = b * 4 + w;
  int q = qt * 32 + lo32;
  short8 zz = {};
  short8 b1 = *(const short8*)((hi ? QM : QH) + (size_t)q * 8);
  short8 b3 = *(const short8*)((hi ? QL : QH) + (size_t)q * 8);
  short8 b4v = *(const short8*)(Q4 + (size_t)q * 8);
  short8 b4 = hi ? zz : b4v;
  short8 b_one = zz;
  if (!hi) { b_one[0] = (short)0x3F80; b_one[1] = (short)0x3F80; }
  float Tv = T[q];
  const float C2 = -14.4269504088896340736f;  // -ALPHA * log2(e)
  float num = 0.f, den = 0.f;
  const int ROWS2 = MDB / NC2;
  int r0 = c * ROWS2;
#pragma unroll 2
  for (int tt = 0; tt < ROWS2 / 32; ++tt) {
    int r = r0 + tt * 32 + lo32;
    short8 a1 = *(const short8*)(DBH + (size_t)r * 8);
    short8 a2 = *(const short8*)(DBM + (size_t)r * 8);
    short8 a3 = *(const short8*)((hi ? DBH : DBL) + (size_t)r * 8);
    short8 a4 = *(const short8*)(DB4 + (size_t)r * 8);
    unsigned lu = LBL2[r];
    short8 a_lab = zz;
    a_lab[0] = (short)(lu & 0xFFFFu);
    a_lab[1] = (short)(lu >> 16);
    f32x16 acc = d2_tile(a1, a2, a3, a4, b1, b3, b4);
    f32x16 accL = {};
    accL = __builtin_amdgcn_mfma_f32_32x32x16_bf16(a_lab, b_one, accL, 0, 0, 0);
#pragma unroll
    for (int i = 0; i < 16; ++i) {
      float d2v = acc[i];
      float lb = accL[i];
      float arg = (d2v <= Tv) ? d2v * C2 : -1.0e4f;
      float wgt = exp2f(arg);
      num = fmaf(wgt, lb, num);
      den += wgt;
    }
  }
  num += __shfl_xor(num, 32);
  den += __shfl_xor(den, 32);
  if (l < 32) nd[(size_t)c * NVOX + q] = make_float2(num, den);
}

// ---------------- final reduction over phase-2 chunks ----------------
__global__ __launch_bounds__(256) void k_out(
    const float2* __restrict__ nd_in, float* __restrict__ out) {
  int v = blockIdx.x * 256 + threadIdx.x;
  float num = 0.f, den = 0.f;
#pragma unroll
  for (int c = 0; c < NC2; ++c) {
    float2 p = nd_in[(size_t)c * NVOX + v];
    num += p.x;
    den += p.y;
  }
  out[v] = num / (den + 1e-8f);
}

extern "C" void kernel_launch(void* const* d_in, const int* in_sizes, int n_in,
                              void* d_out, int out_size, void* d_ws, size_t ws_size,
                              hipStream_t stream) {
  const float* bg = (const float*)d_in[0];
  const float* ed = (const float*)d_in[1];
  const float* w1 = (const float*)d_in[3];
  const float* b1 = (const float*)d_in[4];
  const float* g1 = (const float*)d_in[5];
  const float* be1 = (const float*)d_in[6];
  const float* m1 = (const float*)d_in[7];
  const float* v1 = (const float*)d_in[8];
  const float* w2 = (const float*)d_in[9];
  const float* b2 = (const float*)d_in[10];
  const float* g2 = (const float*)d_in[11];
  const float* be2 = (const float*)d_in[12];
  const float* m2 = (const float*)d_in[13];
  const float* v2 = (const float*)d_in[14];
  const float* w3 = (const float*)d_in[15];
  const float* b3 = (const float*)d_in[16];
  const float* db = (const float*)d_in[17];
  const float* labels = (const float*)d_in[18];
  float* out = (float*)d_out;

  char* ws = (char*)d_ws;
  // layout (regions reused when dead):
  //  [0,2M)       A (conv1 out) -> later QH/QM/QL/Q4 (4x512KB)
  //  [2M,6M)      B (conv2 out)
  //  [6M,6.5M)    DBH/DBM/DBL/DB4 (4x64KB) + LBL2 (16KB)
  //  [6.5M,...)   pk (NC1*10*NVOX*4); then T (128KB)
  //  nd (NC2*NVOX*8 = 2MB) reuses pk base after merge1
  const size_t MB = 1024 * 1024;
  float* A = (float*)(ws + 0);
  float* B = (float*)(ws + 2 * MB);
  unsigned short* QH = (unsigned short*)(ws + 0);
  unsigned short* QM = QH + (size_t)NVOX * 8;
  unsigned short* QL = QM + (size_t)NVOX * 8;
  unsigned short* Q4 = QL + (size_t)NVOX * 8;
  unsigned short* DBH = (unsigned short*)(ws + 6 * MB);
  unsigned short* DBM = DBH + (size_t)MDB * 8;
  unsigned short* DBL = DBM + (size_t)MDB * 8;
  unsigned short* DB4 = DBL + (size_t)MDB * 8;
  unsigned* LBL2 = (unsigned*)(DB4 + (size_t)MDB * 8);
  const size_t off_pk = 6 * MB + 512 * 1024;

  // phase-1 chunk count: prefer 8 (32 waves/CU) if workspace allows
  int NC1 = 4;
  if (ws_size >= off_pk + (size_t)8 * 10 * NVOX * 4 + (size_t)NVOX * 4)
    NC1 = 8;
  float* pk = (float*)(ws + off_pk);
  float* T = (float*)(ws + off_pk + (size_t)NC1 * 10 * NVOX * 4);
  float2* nd = (float2*)(ws + off_pk);  // pk dead after merge1

  k_conv1p<<<144, 256, 0, stream>>>(bg, ed, w1, b1, g1, be1, m1, v1, A, db,
                                    labels, DBH, DBM, DBL, DB4, LBL2);
  k_conv2<<<4 * 128, 256, 0, stream>>>(A, w2, b2, g2, be2, m2, v2, B);
  k_conv3q<<<NVOX / 256, 256, 0, stream>>>(B, w3, b3, QH, QM, QL, Q4);
  k_knn1<<<NC1 * 256, 256, 0, stream>>>(QH, QM, QL, Q4, DBH, DBM, DBL, DB4, pk,
                                        MDB / NC1);
  k_merge1<<<NVOX / 256, 256, 0, stream>>>(pk, T, NC1);
  k_knn2<<<NC2 * 256, 256, 0, stream>>>(QH, QM, QL, Q4, DBH, DBM, DBL, DB4,
                                        LBL2, T, nd);
  k_out<<<NVOX / 256, 256, 0, stream>>>(nd, out);
}

// Round 5
// 166.377 us; speedup vs baseline: 1.5565x; 1.0821x over previous
//
#include <hip/hip_runtime.h>

#define ALPHA 10.0f
#define BN_EPS 1e-5f
#define NVOX 32768   // 32*32*32
#define MDB 4096

typedef __attribute__((ext_vector_type(8))) short short8;
typedef __attribute__((ext_vector_type(16))) float f32x16;

// ---------- 3-way bf16 split helpers ----------
__device__ __forceinline__ unsigned short bfr(float x) {
  unsigned u = __float_as_uint(x);
  return (unsigned short)((u + 0x7FFFu + ((u >> 16) & 1u)) >> 16);
}
__device__ __forceinline__ void split3(float x, unsigned short& h,
                                       unsigned short& m, unsigned short& l) {
  h = bfr(x);
  float fh = __uint_as_float((unsigned)h << 16);
  float x1 = x - fh;
  m = bfr(x1);
  float fm = __uint_as_float((unsigned)m << 16);
  l = bfr(x1 - fm);
}

// d2 tile: acc = (-2 db)·q  [hh+hm | mh+mm | lh+hl]  + dbdb + qq
// One shared sequence -> bit-identical d2 in phase 1 and phase 2.
__device__ __forceinline__ f32x16 d2_tile(short8 a1, short8 a2, short8 a3,
                                          short8 a4, short8 b1, short8 b3,
                                          short8 b4) {
  f32x16 acc = {};
  acc = __builtin_amdgcn_mfma_f32_32x32x16_bf16(a4, b4, acc, 0, 0, 0);
  acc = __builtin_amdgcn_mfma_f32_32x32x16_bf16(a3, b3, acc, 0, 0, 0);
  acc = __builtin_amdgcn_mfma_f32_32x32x16_bf16(a2, b1, acc, 0, 0, 0);
  acc = __builtin_amdgcn_mfma_f32_32x32x16_bf16(a1, b1, acc, 0, 0, 0);
  return acc;
}

__device__ __forceinline__ float fmin3(float a, float b, float c) {
  return fminf(fminf(a, b), c);  // fuses to v_min3_f32
}

// Insert a PAIR of values into sorted-ascending d[0..9] (keep 10 smallest).
#define INSERT2(d, va, vb)                                              \
  do {                                                                  \
    float _lo = fminf((va), (vb)), _hi = fmaxf((va), (vb));             \
    _Pragma("unroll")                                                   \
    for (int _k = 9; _k >= 2; --_k)                                     \
      d[_k] = fmin3(d[_k], fmaxf(d[_k - 1], _lo), fmaxf(d[_k - 2], _hi)); \
    d[1] = fmin3(d[1], fmaxf(d[0], _lo), _hi);                          \
    d[0] = fminf(d[0], _lo);                                            \
  } while (0)

// ------- conv1 (blocks 0..127) + db/label prep (blocks 128..143) -------
__global__ __launch_bounds__(256) void k_conv1p(
    const float* __restrict__ bg, const float* __restrict__ ed,
    const float* __restrict__ w1, const float* __restrict__ b1,
    const float* __restrict__ g1, const float* __restrict__ be1,
    const float* __restrict__ m1, const float* __restrict__ v1,
    float* __restrict__ A, const float* __restrict__ db,
    const float* __restrict__ labels, unsigned short* __restrict__ DBH,
    unsigned short* __restrict__ DBM, unsigned short* __restrict__ DBL,
    unsigned short* __restrict__ DB4, unsigned* __restrict__ LBL2) {
  int t = threadIdx.x;
  if (blockIdx.x >= 128) {  // ---- prep path ----
    int j = (blockIdx.x - 128) * 256 + t;
    float4 x0 = ((const float4*)(db + (size_t)j * 8))[0];
    float4 x1 = ((const float4*)(db + (size_t)j * 8))[1];
    float x[8] = {x0.x, x0.y, x0.z, x0.w, x1.x, x1.y, x1.z, x1.w};
    float ss = x[0] * x[0];
#pragma unroll
    for (int i = 1; i < 8; ++i) ss = fmaf(x[i], x[i], ss);
    short8 sh = {}, sm = {}, sl = {};
#pragma unroll
    for (int i = 0; i < 8; ++i) {
      unsigned short h, m, l;
      split3(-2.f * x[i], h, m, l);
      sh[i] = (short)h; sm[i] = (short)m; sl[i] = (short)l;
    }
    unsigned short dh, dm, dl;
    split3(ss, dh, dm, dl);
    short8 s4 = {};
    s4[0] = (short)dh; s4[1] = (short)dm; s4[2] = (short)dl;
    s4[3] = (short)0x3F80; s4[4] = (short)0x3F80; s4[5] = (short)0x3F80;
    *(short8*)(DBH + (size_t)j * 8) = sh;
    *(short8*)(DBM + (size_t)j * 8) = sm;
    *(short8*)(DBL + (size_t)j * 8) = sl;
    *(short8*)(DB4 + (size_t)j * 8) = s4;
    float lb = labels[j];
    unsigned short lh = bfr(lb);
    float lf = __uint_as_float((unsigned)lh << 16);
    unsigned short ll = bfr(lb - lf);
    LBL2[j] = (unsigned)lh | ((unsigned)ll << 16);
    return;
  }
  // ---- conv1 path ----
  __shared__ float wT[54 * 16];
  __shared__ float sc[16], shs[16];
  for (int i = t; i < 864; i += 256) {
    int o = i & 15, r = i >> 4;
    wT[i] = w1[o * 54 + r];
  }
  if (t < 16) {
    float s = g1[t] * rsqrtf(v1[t] + BN_EPS);
    sc[t] = s;
    shs[t] = (b1[t] - m1[t]) * s + be1[t];
  }
  __syncthreads();
  int v = blockIdx.x * 256 + t;
  int x = v & 31, y = (v >> 5) & 31, z = v >> 10;
  float acc[16];
#pragma unroll
  for (int o = 0; o < 16; ++o) acc[o] = 0.f;
#pragma unroll 1
  for (int k = 0; k < 27; ++k) {
    int dz = k / 9 - 1, dy = (k / 3) % 3 - 1, dx = k % 3 - 1;
    int zz = z + dz, yy = y + dy, xx = x + dx;
    bool inb = (unsigned)zz < 32u && (unsigned)yy < 32u && (unsigned)xx < 32u;
    int vv = zz * 1024 + yy * 32 + xx;
#pragma unroll
    for (int c = 0; c < 2; ++c) {
      const float* in = c ? ed : bg;
      float val = inb ? in[vv] : 0.f;
      const float4* wp = (const float4*)&wT[(c * 27 + k) * 16];
      float4 wa = wp[0], wb = wp[1], wc = wp[2], wd = wp[3];
      acc[0] = fmaf(val, wa.x, acc[0]);  acc[1] = fmaf(val, wa.y, acc[1]);
      acc[2] = fmaf(val, wa.z, acc[2]);  acc[3] = fmaf(val, wa.w, acc[3]);
      acc[4] = fmaf(val, wb.x, acc[4]);  acc[5] = fmaf(val, wb.y, acc[5]);
      acc[6] = fmaf(val, wb.z, acc[6]);  acc[7] = fmaf(val, wb.w, acc[7]);
      acc[8] = fmaf(val, wc.x, acc[8]);  acc[9] = fmaf(val, wc.y, acc[9]);
      acc[10] = fmaf(val, wc.z, acc[10]); acc[11] = fmaf(val, wc.w, acc[11]);
      acc[12] = fmaf(val, wd.x, acc[12]); acc[13] = fmaf(val, wd.y, acc[13]);
      acc[14] = fmaf(val, wd.z, acc[14]); acc[15] = fmaf(val, wd.w, acc[15]);
    }
  }
#pragma unroll
  for (int o = 0; o < 16; ++o) {
    float y2 = fmaf(acc[o], sc[o], shs[o]);
    A[o * NVOX + v] = y2 > 0.f ? y2 : 0.f;
  }
}

// -------- conv2: 16->32, k3, pad1, +BN+ReLU; 8 out-ch per block-group -----
__global__ __launch_bounds__(256) void k_conv2(
    const float* __restrict__ A, const float* __restrict__ w2,
    const float* __restrict__ b2, const float* __restrict__ g2,
    const float* __restrict__ be2, const float* __restrict__ m2,
    const float* __restrict__ v2, float* __restrict__ B) {
  __shared__ float wT[432 * 8];
  __shared__ float sc[8], shs[8];
  int t = threadIdx.x;
  int og = blockIdx.x >> 7;
  int vb = blockIdx.x & 127;
  for (int i = t; i < 3456; i += 256) {
    int o = i & 7, r = i >> 3;
    wT[i] = w2[(og * 8 + o) * 432 + r];
  }
  if (t < 8) {
    int o = og * 8 + t;
    float s = g2[o] * rsqrtf(v2[o] + BN_EPS);
    sc[t] = s;
    shs[t] = (b2[o] - m2[o]) * s + be2[o];
  }
  __syncthreads();
  int v = vb * 256 + t;
  int x = v & 31, y = (v >> 5) & 31, z = v >> 10;
  float acc[8];
#pragma unroll
  for (int o = 0; o < 8; ++o) acc[o] = 0.f;
#pragma unroll 1
  for (int k = 0; k < 27; ++k) {
    int dz = k / 9 - 1, dy = (k / 3) % 3 - 1, dx = k % 3 - 1;
    int zz = z + dz, yy = y + dy, xx = x + dx;
    bool inb = (unsigned)zz < 32u && (unsigned)yy < 32u && (unsigned)xx < 32u;
    int vv = zz * 1024 + yy * 32 + xx;
#pragma unroll
    for (int ci = 0; ci < 16; ++ci) {
      float val = inb ? A[ci * NVOX + vv] : 0.f;
      const float4* wp = (const float4*)&wT[(ci * 27 + k) * 8];
      float4 wa = wp[0], wb = wp[1];
      acc[0] = fmaf(val, wa.x, acc[0]); acc[1] = fmaf(val, wa.y, acc[1]);
      acc[2] = fmaf(val, wa.z, acc[2]); acc[3] = fmaf(val, wa.w, acc[3]);
      acc[4] = fmaf(val, wb.x, acc[4]); acc[5] = fmaf(val, wb.y, acc[5]);
      acc[6] = fmaf(val, wb.z, acc[6]); acc[7] = fmaf(val, wb.w, acc[7]);
    }
  }
#pragma unroll
  for (int o = 0; o < 8; ++o) {
    float y2 = fmaf(acc[o], sc[o], shs[o]);
    B[(og * 8 + o) * NVOX + v] = y2 > 0.f ? y2 : 0.f;
  }
}

// ---- conv3 (1x1x1) 32->8 + L2 normalize + emit bf16 query fragments ----
__global__ __launch_bounds__(256) void k_conv3q(
    const float* __restrict__ B, const float* __restrict__ w3,
    const float* __restrict__ b3, unsigned short* __restrict__ QH,
    unsigned short* __restrict__ QM, unsigned short* __restrict__ QL,
    unsigned short* __restrict__ Q4) {
  __shared__ float wT[32 * 8];
  __shared__ float bL[8];
  int t = threadIdx.x;
  {
    int o = t & 7, ci = t >> 3;
    wT[t] = w3[o * 32 + ci];
  }
  if (t < 8) bL[t] = b3[t];
  __syncthreads();
  int v = blockIdx.x * 256 + t;
  float lat[8];
#pragma unroll
  for (int o = 0; o < 8; ++o) lat[o] = bL[o];
#pragma unroll 4
  for (int ci = 0; ci < 32; ++ci) {
    float val = B[ci * NVOX + v];
    const float4* wp = (const float4*)&wT[ci * 8];
    float4 wa = wp[0], wb = wp[1];
    lat[0] = fmaf(val, wa.x, lat[0]); lat[1] = fmaf(val, wa.y, lat[1]);
    lat[2] = fmaf(val, wa.z, lat[2]); lat[3] = fmaf(val, wa.w, lat[3]);
    lat[4] = fmaf(val, wb.x, lat[4]); lat[5] = fmaf(val, wb.y, lat[5]);
    lat[6] = fmaf(val, wb.z, lat[6]); lat[7] = fmaf(val, wb.w, lat[7]);
  }
  float n2 = 0.f;
#pragma unroll
  for (int o = 0; o < 8; ++o) n2 = fmaf(lat[o], lat[o], n2);
  float inv = 1.f / fmaxf(sqrtf(n2), 1e-12f);
  float q[8];
#pragma unroll
  for (int o = 0; o < 8; ++o) q[o] = lat[o] * inv;
  float qq = q[0] * q[0];
#pragma unroll
  for (int o = 1; o < 8; ++o) qq = fmaf(q[o], q[o], qq);
  short8 sh = {}, sm = {}, sl = {};
#pragma unroll
  for (int o = 0; o < 8; ++o) {
    unsigned short h, m, l;
    split3(q[o], h, m, l);
    sh[o] = (short)h; sm[o] = (short)m; sl[o] = (short)l;
  }
  unsigned short qh, qm, ql;
  split3(qq, qh, qm, ql);
  short8 s4 = {};
  s4[0] = (short)0x3F80; s4[1] = (short)0x3F80; s4[2] = (short)0x3F80;
  s4[3] = (short)qh; s4[4] = (short)qm; s4[5] = (short)ql;
  *(short8*)(QH + (size_t)v * 8) = sh;
  *(short8*)(QM + (size_t)v * 8) = sm;
  *(short8*)(QL + (size_t)v * 8) = sl;
  *(short8*)(Q4 + (size_t)v * 8) = s4;
}

// ===== fused kNN: block = 32 queries; 4 waves x 1024 rows each =====
// phase 1: per-wave exact top-10 -> LDS merge -> exact T per query
// phase 2: rescan own rows, accumulate exp-weighted labels for d2 <= T
__global__ __launch_bounds__(256) void k_knn_fused(
    const unsigned short* __restrict__ QH, const unsigned short* __restrict__ QM,
    const unsigned short* __restrict__ QL, const unsigned short* __restrict__ Q4,
    const unsigned short* __restrict__ DBH, const unsigned short* __restrict__ DBM,
    const unsigned short* __restrict__ DBL, const unsigned short* __restrict__ DB4,
    const unsigned* __restrict__ LBL2, float* __restrict__ out) {
  __shared__ float lds_top[4][10][32];
  __shared__ float lds_num[4][32];
  __shared__ float lds_den[4][32];
  int t = threadIdx.x, w = t >> 6, l = t & 63;
  int lo32 = l & 31, hi = l >> 5;
  int q = blockIdx.x * 32 + lo32;
  short8 zz = {};
  short8 b1 = *(const short8*)((hi ? QM : QH) + (size_t)q * 8);
  short8 b3 = *(const short8*)((hi ? QL : QH) + (size_t)q * 8);
  short8 b4v = *(const short8*)(Q4 + (size_t)q * 8);
  short8 b4 = hi ? zz : b4v;

  // ---- phase 1: top-10 over rows [w*1024, (w+1)*1024) ----
  float d[10];
#pragma unroll
  for (int k = 0; k < 10; ++k) d[k] = 3.4e38f;
  int r0 = w * 1024;
#pragma unroll 2
  for (int tt = 0; tt < 32; ++tt) {
    int r = r0 + tt * 32 + lo32;
    short8 a1 = *(const short8*)(DBH + (size_t)r * 8);
    short8 a2 = *(const short8*)(DBM + (size_t)r * 8);
    short8 a3 = *(const short8*)((hi ? DBH : DBL) + (size_t)r * 8);
    short8 a4 = *(const short8*)(DB4 + (size_t)r * 8);
    f32x16 acc = d2_tile(a1, a2, a3, a4, b1, b3, b4);
#pragma unroll
    for (int p = 0; p < 8; ++p) INSERT2(d, acc[2 * p], acc[2 * p + 1]);
  }
  // merge the two lane-halves (complementary row subsets, same query)
  {
    float e[10];
#pragma unroll
    for (int k = 0; k < 10; ++k) e[k] = __shfl_xor(d[k], 32);
#pragma unroll
    for (int k = 0; k < 10; k += 2) INSERT2(d, e[k], e[k + 1]);
  }
  if (l < 32) {
#pragma unroll
    for (int k = 0; k < 10; ++k) lds_top[w][k][lo32] = d[k];
  }
  __syncthreads();
  // redundant cross-wave merge (all waves compute identical result)
#pragma unroll
  for (int w2 = 0; w2 < 4; ++w2) {
    if (w2 == w) continue;
#pragma unroll
    for (int k2 = 0; k2 < 10; k2 += 2) {
      float va = lds_top[w2][k2][lo32];
      float vb = lds_top[w2][k2 + 1][lo32];
      INSERT2(d, va, vb);
    }
  }
  float Tv = d[9];  // exact 10th-smallest d2 for query q (block-wide)

  // ---- phase 2: rescan own rows, accumulate ----
  const float C2 = -14.4269504088896340736f;  // -ALPHA * log2(e)
  short8 b_one = zz;
  if (!hi) { b_one[0] = (short)0x3F80; b_one[1] = (short)0x3F80; }
  float num = 0.f, den = 0.f;
#pragma unroll 2
  for (int tt = 0; tt < 32; ++tt) {
    int r = r0 + tt * 32 + lo32;
    short8 a1 = *(const short8*)(DBH + (size_t)r * 8);
    short8 a2 = *(const short8*)(DBM + (size_t)r * 8);
    short8 a3 = *(const short8*)((hi ? DBH : DBL) + (size_t)r * 8);
    short8 a4 = *(const short8*)(DB4 + (size_t)r * 8);
    unsigned lu = LBL2[r];
    short8 a_lab = zz;
    a_lab[0] = (short)(lu & 0xFFFFu);
    a_lab[1] = (short)(lu >> 16);
    f32x16 acc = d2_tile(a1, a2, a3, a4, b1, b3, b4);
    f32x16 accL = {};
    accL = __builtin_amdgcn_mfma_f32_32x32x16_bf16(a_lab, b_one, accL, 0, 0, 0);
#pragma unroll
    for (int i = 0; i < 16; ++i) {
      float d2v = acc[i];
      float lb = accL[i];
      float arg = (d2v <= Tv) ? d2v * C2 : -1.0e4f;
      float wgt = exp2f(arg);
      num = fmaf(wgt, lb, num);
      den += wgt;
    }
  }
  num += __shfl_xor(num, 32);
  den += __shfl_xor(den, 32);
  if (l < 32) {
    lds_num[w][lo32] = num;
    lds_den[w][lo32] = den;
  }
  __syncthreads();
  if (t < 32) {
    float nn = lds_num[0][t] + lds_num[1][t] + lds_num[2][t] + lds_num[3][t];
    float dd = lds_den[0][t] + lds_den[1][t] + lds_den[2][t] + lds_den[3][t];
    out[blockIdx.x * 32 + t] = nn / (dd + 1e-8f);
  }
}

extern "C" void kernel_launch(void* const* d_in, const int* in_sizes, int n_in,
                              void* d_out, int out_size, void* d_ws, size_t ws_size,
                              hipStream_t stream) {
  const float* bg = (const float*)d_in[0];
  const float* ed = (const float*)d_in[1];
  const float* w1 = (const float*)d_in[3];
  const float* b1 = (const float*)d_in[4];
  const float* g1 = (const float*)d_in[5];
  const float* be1 = (const float*)d_in[6];
  const float* m1 = (const float*)d_in[7];
  const float* v1 = (const float*)d_in[8];
  const float* w2 = (const float*)d_in[9];
  const float* b2 = (const float*)d_in[10];
  const float* g2 = (const float*)d_in[11];
  const float* be2 = (const float*)d_in[12];
  const float* m2 = (const float*)d_in[13];
  const float* v2 = (const float*)d_in[14];
  const float* w3 = (const float*)d_in[15];
  const float* b3 = (const float*)d_in[16];
  const float* db = (const float*)d_in[17];
  const float* labels = (const float*)d_in[18];
  float* out = (float*)d_out;

  char* ws = (char*)d_ws;
  // layout:
  //  [0,2M)     A (conv1 out) -> later QH/QM/QL/Q4 (4x512KB)
  //  [2M,6M)    B (conv2 out)
  //  [6M,6.5M)  DBH/DBM/DBL/DB4 (4x64KB) + LBL2 (16KB)
  const size_t MB = 1024 * 1024;
  float* A = (float*)(ws + 0);
  float* B = (float*)(ws + 2 * MB);
  unsigned short* QH = (unsigned short*)(ws + 0);
  unsigned short* QM = QH + (size_t)NVOX * 8;
  unsigned short* QL = QM + (size_t)NVOX * 8;
  unsigned short* Q4 = QL + (size_t)NVOX * 8;
  unsigned short* DBH = (unsigned short*)(ws + 6 * MB);
  unsigned short* DBM = DBH + (size_t)MDB * 8;
  unsigned short* DBL = DBM + (size_t)MDB * 8;
  unsigned short* DB4 = DBL + (size_t)MDB * 8;
  unsigned* LBL2 = (unsigned*)(DB4 + (size_t)MDB * 8);

  k_conv1p<<<144, 256, 0, stream>>>(bg, ed, w1, b1, g1, be1, m1, v1, A, db,
                                    labels, DBH, DBM, DBL, DB4, LBL2);
  k_conv2<<<4 * 128, 256, 0, stream>>>(A, w2, b2, g2, be2, m2, v2, B);
  k_conv3q<<<NVOX / 256, 256, 0, stream>>>(B, w3, b3, QH, QM, QL, Q4);
  k_knn_fused<<<NVOX / 32, 256, 0, stream>>>(QH, QM, QL, Q4, DBH, DBM, DBL,
                                             DB4, LBL2, out);
}